// Round 11
// baseline (25.880 us; speedup 1.0000x reference)
//
#include <hip/hip_runtime.h>

typedef float f32x4 __attribute__((ext_vector_type(4)));

#define B_ 8
#define N_ 256
#define D_ 128

// ---------------------------------------------------------------------------
// Single dispatch, zero inter-block deps. 256 blocks x 512 threads.
// Block: b = bid&7 (XCD-affine), f0 = (bid>>3)*4 -> 4 feature cols.
// Register-blocked to minimize LDS instruction count (~800/block vs ~2100):
// Phase 1: thread = (rq: 4 rows, hq: a/c half, dq: d-quarter of 32).
//   32 broadcast W-reads/thread, each feeding 4 rows (16 FMA lanes).
//   Single-stage LDS combine over the 4 d-quarters -> AS (a+bias) / CS (c).
// Phase 2: thread = (rg: 4 rows, jg: j-octant of 32).
//   32 broadcast CS-reads/thread, each feeding 4 rows x 3 packed ops.
//   3-stage LDS tree over the 8 j-octants; jg==0 stores out.
// ---------------------------------------------------------------------------
__global__ __launch_bounds__(512) void onepass_rb_kernel(
    const float* __restrict__ x, const float* __restrict__ W,
    const float* __restrict__ bias, float* __restrict__ out) {

    __shared__ f32x4 Wc[256];    // 4 KB   W rows 0..255, cols f0..f0+3
    __shared__ f32x4 AS[256];    // 4 KB   a + bias
    __shared__ f32x4 CS[256];    // 4 KB   c
    __shared__ f32x4 PR[1536];   // 24 KB  combine scratch (both phases)

    const int tid = threadIdx.x;
    const int bid = blockIdx.x;
    const int b   = bid & 7;
    const int f0  = (bid >> 3) * 4;

    if (tid < 256) {
        Wc[tid] = *reinterpret_cast<const f32x4*>(W + (size_t)tid * D_ + f0);
    }
    __syncthreads();

    // ---- phase 1: GEMM, register-blocked 4 rows x 32 d ----
    const int rq = tid & 63;          // rows rq*4 .. rq*4+3
    const int hq = (tid >> 6) & 1;    // 0 = a (W rows 0..127), 1 = c (128..255)
    const int dq = tid >> 7;          // 0..3 -> d range dq*32 .. +31

    f32x4 acc[4] = {};
    {
        const float* __restrict__ xbase =
            x + ((size_t)b * N_ + rq * 4) * D_ + dq * 32;
        const f32x4* __restrict__ Wh = &Wc[hq * 128 + dq * 32];
        #pragma unroll
        for (int c = 0; c < 8; ++c) {          // 8 chunks of 4 d
            f32x4 xv[4];
            #pragma unroll
            for (int k = 0; k < 4; ++k)
                xv[k] = *reinterpret_cast<const f32x4*>(
                    xbase + (size_t)k * D_ + c * 4);
            #pragma unroll
            for (int dd = 0; dd < 4; ++dd) {
                const f32x4 wv = Wh[c * 4 + dd];   // broadcast LDS read
                #pragma unroll
                for (int k = 0; k < 4; ++k)
                    acc[k] += xv[k][dd] * wv;
            }
        }
    }

    // combine d-quarters: single stage (dq>0 write, dq==0 read 12)
    if (dq > 0) {
        #pragma unroll
        for (int k = 0; k < 4; ++k)
            PR[((dq - 1) * 128 + hq * 64 + rq) * 4 + k] = acc[k];
    }
    __syncthreads();
    if (dq == 0) {
        #pragma unroll
        for (int s = 0; s < 3; ++s)
            #pragma unroll
            for (int k = 0; k < 4; ++k)
                acc[k] += PR[(s * 128 + hq * 64 + rq) * 4 + k];
        if (hq == 0) {
            const f32x4 bv = *reinterpret_cast<const f32x4*>(bias + f0);
            #pragma unroll
            for (int k = 0; k < 4; ++k) AS[rq * 4 + k] = acc[k] + bv;
        } else {
            #pragma unroll
            for (int k = 0; k < 4; ++k) CS[rq * 4 + k] = acc[k];
        }
    }
    __syncthreads();

    // ---- phase 2: reduce, register-blocked 4 rows x 32 j ----
    const int rg = tid & 63;          // rows rg*4 .. rg*4+3
    const int jg = tid >> 6;          // 0..7 -> j range jg*32 .. +31
    const f32x4 zero = {0.f, 0.f, 0.f, 0.f};

    f32x4 av[4], s2[4];
    #pragma unroll
    for (int k = 0; k < 4; ++k) { av[k] = AS[rg * 4 + k]; s2[k] = zero; }

    const f32x4* __restrict__ Cj = &CS[jg * 32];
    #pragma unroll 8
    for (int j = 0; j < 32; ++j) {
        const f32x4 cv = Cj[j];                // broadcast LDS read
        #pragma unroll
        for (int k = 0; k < 4; ++k)
            s2[k] += __builtin_elementwise_max(av[k] + cv, zero);
    }

    // tree over the 8 j-octants
    #pragma unroll
    for (int s = 4; s >= 1; s >>= 1) {
        if (jg >= s && jg < 2 * s) {
            #pragma unroll
            for (int k = 0; k < 4; ++k)
                PR[((jg - s) * 64 + rg) * 4 + k] = s2[k];
        }
        __syncthreads();
        if (jg < s) {
            #pragma unroll
            for (int k = 0; k < 4; ++k)
                s2[k] += PR[(jg * 64 + rg) * 4 + k];
        }
        __syncthreads();
    }

    if (jg == 0) {
        #pragma unroll
        for (int k = 0; k < 4; ++k)
            *reinterpret_cast<f32x4*>(
                out + ((size_t)b * N_ + rg * 4 + k) * D_ + f0) = s2[k];
    }
}

extern "C" void kernel_launch(void* const* d_in, const int* in_sizes, int n_in,
                              void* d_out, int out_size, void* d_ws, size_t ws_size,
                              hipStream_t stream) {
    const float* x    = (const float*)d_in[0];   // (B, N, D) fp32
    const float* W    = (const float*)d_in[1];   // (2D, D)   fp32
    const float* bias = (const float*)d_in[2];   // (D,)      fp32
    float* out = (float*)d_out;                  // (B, N, D) fp32

    onepass_rb_kernel<<<B_ * (D_ / 4), 512, 0, stream>>>(x, W, bias, out);
}

// Round 12
// 19.338 us; speedup vs baseline: 1.3383x; 1.3383x over previous
//
#include <hip/hip_runtime.h>

typedef float f32x4 __attribute__((ext_vector_type(4)));

#define B_ 8
#define N_ 256
#define D_ 128

// ---------------------------------------------------------------------------
// Single dispatch, zero inter-block deps, 3 barriers. 256 blocks x 512 thr.
// Block: b = bid&7 (XCD-affine), f0 = (bid>>3)*4 -> 4 feature cols.
// Phase 1 (no redundant compute): thread (r=tid&255, half=tid>>8):
//   half=0 -> a[r][f0..3] (+bias) -> LDS AS;  half=1 -> c[r][f0..3] -> LDS CS.
//   W cols staged in LDS Wc once.
// Phase 2: thread (r, half): sum over its 128-j half of relu(AS[r]+CS[j]).
//   CS reads are wave-uniform broadcasts (all lanes same j) -> conflict-free.
//   half=1 publishes partial via LDS PR; half=0 adds and stores out.
// Proven best: 19.20 us (R10). Body ~3.5 us = arithmetic floor; remainder is
// graph-replay fixed cost (dispatch count 1 vs 2 measured identical).
// ---------------------------------------------------------------------------
__global__ __launch_bounds__(512) void onepass_relational_kernel(
    const float* __restrict__ x, const float* __restrict__ W,
    const float* __restrict__ bias, float* __restrict__ out) {

    __shared__ f32x4 Wc[256];   // 4 KB  W[0..255][f0..f0+3]
    __shared__ f32x4 AS[256];   // 4 KB  a + bias
    __shared__ f32x4 CS[256];   // 4 KB  c
    __shared__ f32x4 PR[256];   // 4 KB  partials from half=1

    const int tid = threadIdx.x;
    const int bid = blockIdx.x;
    const int b   = bid & 7;
    const int f0  = (bid >> 3) * 4;

    if (tid < 256) {
        Wc[tid] = *reinterpret_cast<const f32x4*>(W + (size_t)tid * D_ + f0);
    }
    __syncthreads();

    // ---- phase 1: GEMM (a and c columns, non-redundant) ----
    const int r    = tid & 255;        // row 0..255
    const int half = tid >> 8;         // 0 = a (W rows 0..127), 1 = c (128..255)
    const float* __restrict__ xr = x + ((size_t)b * N_ + r) * D_;
    const f32x4* __restrict__ Wh = &Wc[half * 128];

    f32x4 acc = {0.f, 0.f, 0.f, 0.f};
    #pragma unroll 8
    for (int d4 = 0; d4 < 32; ++d4) {
        const f32x4 xv = *reinterpret_cast<const f32x4*>(xr + d4 * 4);
        acc += xv[0] * Wh[d4 * 4 + 0] + xv[1] * Wh[d4 * 4 + 1] +
               xv[2] * Wh[d4 * 4 + 2] + xv[3] * Wh[d4 * 4 + 3];
    }

    if (half) {
        CS[r] = acc;
    } else {
        AS[r] = acc + *reinterpret_cast<const f32x4*>(bias + f0);
    }
    __syncthreads();

    // ---- phase 2: brute reduce, j split across halves ----
    const f32x4 zero = {0.f, 0.f, 0.f, 0.f};
    const f32x4 av = AS[r];
    const f32x4* __restrict__ Cj = &CS[half * 128];
    f32x4 s = zero;
    #pragma unroll 8
    for (int j = 0; j < 128; ++j) {
        s += __builtin_elementwise_max(av + Cj[j], zero);   // broadcast read
    }

    if (half) PR[r] = s;
    __syncthreads();
    if (!half) {
        s += PR[r];
        *reinterpret_cast<f32x4*>(out + ((size_t)b * N_ + r) * D_ + f0) = s;
    }
}

extern "C" void kernel_launch(void* const* d_in, const int* in_sizes, int n_in,
                              void* d_out, int out_size, void* d_ws, size_t ws_size,
                              hipStream_t stream) {
    const float* x    = (const float*)d_in[0];   // (B, N, D) fp32
    const float* W    = (const float*)d_in[1];   // (2D, D)   fp32
    const float* bias = (const float*)d_in[2];   // (D,)      fp32
    float* out = (float*)d_out;                  // (B, N, D) fp32

    onepass_relational_kernel<<<B_ * (D_ / 4), 512, 0, stream>>>(x, W, bias, out);
}